// Round 8
// baseline (153.798 us; speedup 1.0000x reference)
//
#include <hip/hip_runtime.h>
#include <hip/hip_fp16.h>
#include <math.h>

#define Wd 512
#define Hd 512
#define Bd 32
#define PLANE (Hd * Wd)

// k_rotate: 16x16 output tile; rotated-source window <= 15*sqrt(2)+5 -> 26.
#define WND 26
#define STR 27
#define NCELL (WND * STR)        // 702 = 2*256 + 190

// k_affine staging window; scale>=0.9 -> cols<=39, rows<=21
#define RPW 40
#define RPH 22

__device__ __forceinline__ float clip01(float x) { return fminf(fmaxf(x, 0.f), 1.f); }

__device__ __forceinline__ unsigned pack2h(float a, float b) {
    __half2 h = __floats2half2_rn(a, b);
    return *(unsigned*)&h;
}
__device__ __forceinline__ float2 unp2h(unsigned u) {
    return __half22float2(*(__half2*)&u);
}

// ---------------------------------------------------------------------------
// K0: pack f32 planar imgs+mask into pre-flipped AoS fp16 (ushort4 {r,g,b,m}).
// Pure streaming: 4 float4 loads + 2 uint4 stores per thread (4 px).
// ---------------------------------------------------------------------------
__global__ __launch_bounds__(256) void k_pack(const float* __restrict__ imgs,
                                              const float* __restrict__ masks,
                                              const int* __restrict__ hflip,
                                              const int* __restrict__ vflip,
                                              uint2* __restrict__ src)
{
    const int b = blockIdx.y;
    const bool hf = hflip[b] > 0, vf = vflip[b] > 0;
    const int i4 = blockIdx.x * 256 + threadIdx.x;       // group of 4 px
    const int y  = (i4 * 4) >> 9;                        // /Wd
    const int x0 = (i4 * 4) & (Wd - 1);
    const int fy = vf ? (Hd - 1 - y) : y;

    const float* ib = imgs + (size_t)b * 3 * PLANE;
    const float* mb = masks + (size_t)b * PLANE;

    float4 r4, g4, b4, m4;
    if (!hf) {
        int gi = fy * Wd + x0;
        r4 = *(const float4*)(ib + gi);
        g4 = *(const float4*)(ib + gi + PLANE);
        b4 = *(const float4*)(ib + gi + 2 * PLANE);
        m4 = *(const float4*)(mb + gi);
    } else {
        int gi = fy * Wd + (Wd - 4 - x0);
        float4 r = *(const float4*)(ib + gi);
        float4 g = *(const float4*)(ib + gi + PLANE);
        float4 bb = *(const float4*)(ib + gi + 2 * PLANE);
        float4 m = *(const float4*)(mb + gi);
        r4 = make_float4(r.w, r.z, r.y, r.x);
        g4 = make_float4(g.w, g.z, g.y, g.x);
        b4 = make_float4(bb.w, bb.z, bb.y, bb.x);
        m4 = make_float4(m.w, m.z, m.y, m.x);
    }

    uint2 o0 = make_uint2(pack2h(r4.x, g4.x), pack2h(b4.x, m4.x));
    uint2 o1 = make_uint2(pack2h(r4.y, g4.y), pack2h(b4.y, m4.y));
    uint2 o2 = make_uint2(pack2h(r4.z, g4.z), pack2h(b4.z, m4.z));
    uint2 o3 = make_uint2(pack2h(r4.w, g4.w), pack2h(b4.w, m4.w));

    uint2* dst = src + (size_t)b * PLANE + (size_t)i4 * 4;
    dst[0] = o0; dst[1] = o1; dst[2] = o2; dst[3] = o3;
}

// ---------------------------------------------------------------------------
// K1: rotate from pre-flipped AoS fp16 src -> AoS fp16 rot.
// 16x16 tile, 1 px/thread; staging = 1 uint2 load/cell (load-early/write-late).
// ---------------------------------------------------------------------------
__global__ __launch_bounds__(256) void k_rotate(const uint2* __restrict__ src,
                                                const float* __restrict__ angles,
                                                uint2* __restrict__ rot)
{
    __shared__ uint2 tile[NCELL];        // 5616 B

    const int tx = threadIdx.x, ty = threadIdx.y;
    const int tid = ty * 16 + tx;
    const int bx = blockIdx.x * 16, by = blockIdx.y * 16;
    const int b = blockIdx.z;

    const float cx = (Wd - 1) * 0.5f, cy = (Hd - 1) * 0.5f;
    const float th = angles[b] * 0.017453292519943295f;
    const float c = cosf(th), s = sinf(th);

    const float xs0 = (float)bx - cx, xs1 = (float)(bx + 15) - cx;
    const float ys0 = (float)by - cy, ys1 = (float)(by + 15) - cy;
    float a0 = c * xs0 + s * ys0 + cx, a1 = c * xs1 + s * ys0 + cx;
    float a2 = c * xs0 + s * ys1 + cx, a3 = c * xs1 + s * ys1 + cx;
    float b0 = -s * xs0 + c * ys0 + cy, b1 = -s * xs1 + c * ys0 + cy;
    float b2 = -s * xs0 + c * ys1 + cy, b3 = -s * xs1 + c * ys1 + cy;
    const int ox0 = (int)floorf(fminf(fminf(a0, a1), fminf(a2, a3))) - 1;
    const int oy0 = (int)floorf(fminf(fminf(b0, b1), fminf(b2, b3))) - 1;

    const uint2* sb = src + (size_t)b * PLANE;

    // phase 1: all staging loads into registers
    uint2 vb[3];
    #pragma unroll
    for (int it = 0; it < 3; ++it) {
        int idx = tid + it * 256;
        int row = idx / STR;
        int col = idx - row * STR;
        int gy = oy0 + row, gx = ox0 + col;
        uint2 v = make_uint2(0u, 0u);
        if (idx < NCELL && col < WND &&
            (unsigned)gy < (unsigned)Hd && (unsigned)gx < (unsigned)Wd)
            v = sb[gy * Wd + gx];
        vb[it] = v;
    }
    // phase 2: LDS writes
    #pragma unroll
    for (int it = 0; it < 3; ++it) {
        int idx = tid + it * 256;
        if (idx < NCELL) tile[idx] = vb[it];
    }
    __syncthreads();

    const int x = bx + tx, y = by + ty;
    float dx = (float)x - cx, dy = (float)y - cy;
    float sx = c * dx + s * dy + cx;
    float sy = -s * dx + c * dy + cy;
    float sxl = sx - (float)ox0;
    float syl = sy - (float)oy0;
    float x0f = floorf(sxl), y0f = floorf(syl);
    float wx = sxl - x0f, wy = syl - y0f;
    int xi = min(max((int)x0f, 0), WND - 2);
    int yi = min(max((int)y0f, 0), WND - 2);
    float w00 = (1.f - wx) * (1.f - wy);
    float w10 = wx * (1.f - wy);
    float w01 = (1.f - wx) * wy;
    float w11 = wx * wy;
    int base = yi * STR + xi;
    uint2 c00 = tile[base], c10 = tile[base + 1];
    uint2 c01 = tile[base + STR], c11 = tile[base + STR + 1];

    float2 rg00 = unp2h(c00.x), bm00 = unp2h(c00.y);
    float2 rg10 = unp2h(c10.x), bm10 = unp2h(c10.y);
    float2 rg01 = unp2h(c01.x), bm01 = unp2h(c01.y);
    float2 rg11 = unp2h(c11.x), bm11 = unp2h(c11.y);

    float r  = w00 * rg00.x + w10 * rg10.x + w01 * rg01.x + w11 * rg11.x;
    float g  = w00 * rg00.y + w10 * rg10.y + w01 * rg01.y + w11 * rg11.y;
    float bl = w00 * bm00.x + w10 * bm10.x + w01 * bm01.x + w11 * bm11.x;
    float m  = w00 * bm00.y + w10 * bm10.y + w01 * bm01.y + w11 * bm11.y;

    rot[(size_t)b * PLANE + (size_t)y * Wd + x] =
        make_uint2(pack2h(r, g), pack2h(bl, m));
}

// ---------------------------------------------------------------------------
// K2: affine from AoS fp16 rot + brightness. Writes masks (final) to d_out,
// rgb as packed fp16 planes to ws, and gray partials.
// ---------------------------------------------------------------------------
__global__ __launch_bounds__(256) void k_affine(const ushort4* __restrict__ rot,
                                                const float* __restrict__ translate,
                                                const float* __restrict__ scale,
                                                const float* __restrict__ brightness,
                                                unsigned short* __restrict__ pre,
                                                float* __restrict__ omasks,
                                                float* __restrict__ partials)
{
    __shared__ float4 tile[RPH * RPW];     // 14080 B

    const int tx2 = threadIdx.x;           // 0..15
    const int ty  = threadIdx.y;           // 0..15
    const int tid = ty * 16 + tx2;
    const int bx = blockIdx.x * 32, by = blockIdx.y * 16;
    const int b = blockIdx.z;

    const float cx = (Wd - 1) * 0.5f, cy = (Hd - 1) * 0.5f;
    const float txf = translate[2 * b] * (float)Wd;
    const float tyf = translate[2 * b + 1] * (float)Hd;
    const float sc = scale[b];
    const float bf = brightness[b];

    float ax0 = ((float)bx - cx - txf) / sc + cx;
    float ax1 = ((float)(bx + 31) - cx - txf) / sc + cx;
    float ay0 = ((float)by - cy - tyf) / sc + cy;
    float ay1 = ((float)(by + 15) - cy - tyf) / sc + cy;
    const int rx0 = (int)floorf(fminf(ax0, ax1)) - 1;
    const int ry0 = (int)floorf(fminf(ay0, ay1)) - 1;

    const ushort4* srcp = rot + (size_t)b * PLANE;
    const bool fastp = (rx0 >= 0) && (ry0 >= 0) &&
                       (rx0 + RPW <= Wd) && (ry0 + RPH <= Hd);

    if (fastp) {
        for (int idx = tid; idx < RPH * RPW; idx += 256) {
            int row = idx / RPW;
            int col = idx - row * RPW;
            ushort4 h = srcp[(ry0 + row) * Wd + rx0 + col];
            tile[idx] = make_float4(__half2float(__ushort_as_half(h.x)),
                                    __half2float(__ushort_as_half(h.y)),
                                    __half2float(__ushort_as_half(h.z)),
                                    __half2float(__ushort_as_half(h.w)));
        }
    } else {
        for (int idx = tid; idx < RPH * RPW; idx += 256) {
            int row = idx / RPW;
            int col = idx - row * RPW;
            int gy = ry0 + row, gx = rx0 + col;
            float4 v = make_float4(0.f, 0.f, 0.f, 0.f);
            if ((unsigned)gy < (unsigned)Hd && (unsigned)gx < (unsigned)Wd) {
                ushort4 h = srcp[gy * Wd + gx];
                v = make_float4(__half2float(__ushort_as_half(h.x)),
                                __half2float(__ushort_as_half(h.y)),
                                __half2float(__ushort_as_half(h.z)),
                                __half2float(__ushort_as_half(h.w)));
            }
            tile[idx] = v;
        }
    }
    __syncthreads();

    float grays = 0.f;
    float rr[2], gg[2], bb[2], mm[2];
    #pragma unroll
    for (int k = 0; k < 2; ++k) {
        int x = bx + 2 * tx2 + k, y = by + ty;
        float sx = ((float)x - cx - txf) / sc + cx;
        float sy = ((float)y - cy - tyf) / sc + cy;
        float sxl = sx - (float)rx0, syl = sy - (float)ry0;
        float x0f = floorf(sxl), y0f = floorf(syl);
        float wx = sxl - x0f, wy = syl - y0f;
        int xi = min(max((int)x0f, 0), RPW - 2);
        int yi = min(max((int)y0f, 0), RPH - 2);
        float w00 = (1.f - wx) * (1.f - wy);
        float w10 = wx * (1.f - wy);
        float w01 = (1.f - wx) * wy;
        float w11 = wx * wy;
        int base = yi * RPW + xi;
        float4 v00 = tile[base], v10 = tile[base + 1];
        float4 v01 = tile[base + RPW], v11 = tile[base + RPW + 1];
        float r  = w00 * v00.x + w10 * v10.x + w01 * v01.x + w11 * v11.x;
        float g  = w00 * v00.y + w10 * v10.y + w01 * v01.y + w11 * v11.y;
        float b2 = w00 * v00.z + w10 * v10.z + w01 * v01.z + w11 * v11.z;
        float m  = w00 * v00.w + w10 * v10.w + w01 * v01.w + w11 * v11.w;
        r = clip01(r * bf);
        g = clip01(g * bf);
        b2 = clip01(b2 * bf);
        rr[k] = r; gg[k] = g; bb[k] = b2; mm[k] = m;
        grays += 0.299f * r + 0.587f * g + 0.114f * b2;
    }
    {
        size_t pix = (size_t)(by + ty) * Wd + bx + 2 * tx2;       // even
        unsigned short* pb = pre + (size_t)b * 3 * PLANE;
        *(unsigned*)(pb + pix)             = pack2h(rr[0], rr[1]);
        *(unsigned*)(pb + PLANE + pix)     = pack2h(gg[0], gg[1]);
        *(unsigned*)(pb + 2 * PLANE + pix) = pack2h(bb[0], bb[1]);
        *(float2*)(omasks + (size_t)b * PLANE + pix) = make_float2(mm[0], mm[1]);
    }

    __syncthreads();
    float* sred = (float*)tile;
    sred[tid] = grays;
    __syncthreads();
    for (int off = 128; off > 0; off >>= 1) {
        if (tid < off) sred[tid] += sred[tid + off];
        __syncthreads();
    }
    if (tid == 0)
        partials[(size_t)b * 512 + blockIdx.y * 16 + blockIdx.x] = sred[0];
}

__global__ __launch_bounds__(256) void k_mean(const float* __restrict__ partials,
                                              float* __restrict__ means)
{
    int b = blockIdx.x;
    int t = threadIdx.x;
    float s = partials[(size_t)b * 512 + t] + partials[(size_t)b * 512 + t + 256];
    __shared__ float sr[256];
    sr[t] = s;
    __syncthreads();
    for (int off = 128; off > 0; off >>= 1) {
        if (t < off) sr[t] += sr[t + off];
        __syncthreads();
    }
    if (t == 0) means[b] = sr[0] * (1.f / (float)PLANE);
}

__device__ __forceinline__ void jit1(float& r, float& g, float& bl,
                                     float mean, float cf, float sf, float hsh)
{
    r  = clip01(cf * r + (1.f - cf) * mean);
    g  = clip01(cf * g + (1.f - cf) * mean);
    bl = clip01(cf * bl + (1.f - cf) * mean);

    float gray = 0.299f * r + 0.587f * g + 0.114f * bl;
    r  = clip01(sf * r + (1.f - sf) * gray);
    g  = clip01(sf * g + (1.f - sf) * gray);
    bl = clip01(sf * bl + (1.f - sf) * gray);

    float maxc = fmaxf(fmaxf(r, g), bl);
    float minc = fminf(fminf(r, g), bl);
    float delta = maxc - minc;
    float sgm = delta / (maxc + 1e-8f);
    float dd = delta + 1e-8f;
    float rc = (maxc - r) / dd;
    float gc = (maxc - g) / dd;
    float bc = (maxc - bl) / dd;
    float h6 = (maxc == r) ? (bc - gc) : ((maxc == g) ? (2.f + rc - bc) : (4.f + gc - rc));
    float h = h6 * (1.f / 6.f);
    h = h - floorf(h);
    h = h + hsh;
    h = h - floorf(h);

    float hi = floorf(h * 6.f);
    float f = h * 6.f - hi;
    float v = maxc;
    float p = v * (1.f - sgm);
    float q = v * (1.f - f * sgm);
    float t = v * (1.f - (1.f - f) * sgm);
    int i = ((int)hi) % 6;
    if (i < 0) i += 6;
    float ro, go, bo;
    switch (i) {
        case 0: ro = v; go = t; bo = p; break;
        case 1: ro = q; go = v; bo = p; break;
        case 2: ro = p; go = v; bo = t; break;
        case 3: ro = p; go = q; bo = v; break;
        case 4: ro = t; go = p; bo = v; break;
        default: ro = v; go = p; bo = q; break;
    }
    r = clip01(ro); g = clip01(go); bl = clip01(bo);
}

__global__ __launch_bounds__(256) void k_jitter(const unsigned short* __restrict__ pre,
                                                const float* __restrict__ means,
                                                const float* __restrict__ contrast,
                                                const float* __restrict__ saturation,
                                                const float* __restrict__ hue,
                                                float* __restrict__ oimgs)
{
    int b = blockIdx.y;
    size_t i4 = (size_t)blockIdx.x * 256 + threadIdx.x;   // group of 4 px
    const unsigned short* pb = pre + (size_t)b * 3 * PLANE;

    uint2 ur = *(const uint2*)(pb + i4 * 4);
    uint2 ug = *(const uint2*)(pb + PLANE + i4 * 4);
    uint2 ub = *(const uint2*)(pb + 2 * PLANE + i4 * 4);

    float2 r01 = unp2h(ur.x), r23 = unp2h(ur.y);
    float2 g01 = unp2h(ug.x), g23 = unp2h(ug.y);
    float2 b01 = unp2h(ub.x), b23 = unp2h(ub.y);

    float4 R  = make_float4(r01.x, r01.y, r23.x, r23.y);
    float4 G  = make_float4(g01.x, g01.y, g23.x, g23.y);
    float4 Bv = make_float4(b01.x, b01.y, b23.x, b23.y);

    float mean = means[b];
    float cf = contrast[b], sf = saturation[b], hsh = hue[b];

    jit1(R.x, G.x, Bv.x, mean, cf, sf, hsh);
    jit1(R.y, G.y, Bv.y, mean, cf, sf, hsh);
    jit1(R.z, G.z, Bv.z, mean, cf, sf, hsh);
    jit1(R.w, G.w, Bv.w, mean, cf, sf, hsh);

    size_t po = (size_t)b * 3 * PLANE + i4 * 4;
    *(float4*)(oimgs + po)             = R;
    *(float4*)(oimgs + po + PLANE)     = G;
    *(float4*)(oimgs + po + 2 * PLANE) = Bv;
}

extern "C" void kernel_launch(void* const* d_in, const int* in_sizes, int n_in,
                              void* d_out, int out_size, void* d_ws, size_t ws_size,
                              hipStream_t stream)
{
    const float* imgs       = (const float*)d_in[0];
    const float* masks      = (const float*)d_in[1];
    const int*   hflip      = (const int*)d_in[2];
    const int*   vflip      = (const int*)d_in[3];
    const float* angles     = (const float*)d_in[4];
    const float* translate  = (const float*)d_in[5];
    const float* scale      = (const float*)d_in[6];
    const float* brightness = (const float*)d_in[7];
    const float* contrast   = (const float*)d_in[8];
    const float* saturation = (const float*)d_in[9];
    const float* hue        = (const float*)d_in[10];

    float* oimgs  = (float*)d_out;
    float* omasks = oimgs + (size_t)Bd * 3 * PLANE;

    // ws layout: src (8B*N, dead after k_rotate) | rot (8B*N) | partials | means
    // pre (fp16 rgb planes, 6B*N) aliases the dead src region.
    uint2* srcp          = (uint2*)d_ws;                                  // 67 MB
    uint2* rot           = srcp + (size_t)Bd * PLANE;                     // 67 MB
    float* partials      = (float*)(rot + (size_t)Bd * PLANE);            // Bd*512
    float* means         = partials + (size_t)Bd * 512;                   // Bd
    unsigned short* pre  = (unsigned short*)d_ws;                         // aliases srcp

    dim3 grd0(PLANE / 4 / 256, Bd);
    k_pack<<<grd0, 256, 0, stream>>>(imgs, masks, hflip, vflip, srcp);

    dim3 blk1(16, 16);
    dim3 grd1(Wd / 16, Hd / 16, Bd);
    k_rotate<<<grd1, blk1, 0, stream>>>(srcp, angles, rot);

    dim3 blk2(16, 16);
    dim3 grd2(Wd / 32, Hd / 16, Bd);
    k_affine<<<grd2, blk2, 0, stream>>>((const ushort4*)rot, translate, scale, brightness,
                                        pre, omasks, partials);

    k_mean<<<Bd, 256, 0, stream>>>(partials, means);

    dim3 grd3(PLANE / 4 / 256, Bd);
    k_jitter<<<grd3, 256, 0, stream>>>(pre, means, contrast, saturation, hue, oimgs);
}